// Round 5
// baseline (598.539 us; speedup 1.0000x reference)
//
#include <hip/hip_runtime.h>

// LSTM B=32768, T=512, I=2, H=16 — MFMA recurrence v6:
// v5 structure (dual sequence groups, stage-vectorized 8 chains, ping-pong
// frags, x/bias folded into MFMA) + v4's TRANSCENDENTAL-FREE activation math
// (precision-proven in r3: passed absmax 0.0039), restructured stage-major
// with DECOUPLED per-chain rcps (v4's cross-tile batch inversion built ~30-hop
// serial chains -> latency bound; that was v4's regression, not the math).
//
// Gate rationals ([5/6] Pade of tanh, exact CF truncation):
//   tanh(y) = y*(10395+1260u+21u^2)/(10395+4725u+210u^2+u^3), u=y^2
//   sigma(x) = 0.5*(1 + tanh(x/2))   (the /2 folded into weight scales)
// Per unit: gates i,f paired (a), g,o paired (b) in f32x2 -> v_pk ops.
//   N*,D* = num/den polys; S* = D*+N*  (so sigma = 0.5*S/D)
//   c-update (state s = 2c):
//     s' = [Sf*s*(Di*Dg) + Si*(2Ng)*Df] * rcp(2*Df*Di*Dg)
//     (2Ng folded into g-component num constants; P2=P+P gives the 2)
//   tanh(c) = tanh(s/2): numc/dc2 polys in w=s^2 (v4 constants), own rcp:
//     h2 = 2h = So*numc*rcp(Do*dc2)
// Per chain: ~39 VALU (16 pk) + 2 rcp; zero exp2. 8 chains stage-major.

#define T_STEPS 512
#define LOG2E 1.44269504088896340736f

typedef __bf16 bf16x8 __attribute__((ext_vector_type(8)));
typedef float  f32x4  __attribute__((ext_vector_type(4)));
typedef float  f32x2  __attribute__((ext_vector_type(2)));
typedef unsigned int u32x4 __attribute__((ext_vector_type(4)));

union frag_u { u32x4 u; bf16x8 v; };

#if __has_builtin(__builtin_amdgcn_exp2f)
__device__ __forceinline__ float fexp2(float x) { return __builtin_amdgcn_exp2f(x); }
#else
__device__ __forceinline__ float fexp2(float x) { return exp2f(x); }
#endif
#if __has_builtin(__builtin_amdgcn_rcpf)
__device__ __forceinline__ float frcp(float x) { return __builtin_amdgcn_rcpf(x); }
#else
__device__ __forceinline__ float frcp(float x) { return 1.0f / x; }
#endif

// (hi,hi) duplicate of the bf16-truncated value: one v_perm.
__device__ __forceinline__ unsigned dup_hi(float h) {
    unsigned hb = __float_as_uint(h);
#if __has_builtin(__builtin_amdgcn_perm)
    return __builtin_amdgcn_perm(hb, hb, 0x03020302u);
#else
    return (hb >> 16) | (hb & 0xFFFF0000u);
#endif
}
// low16 = bf16(res) of h, high16 = high16 of xq (x part, bf16-in-high16).
__device__ __forceinline__ unsigned lo_with_x(float res, unsigned xq) {
#if __has_builtin(__builtin_amdgcn_perm)
    return __builtin_amdgcn_perm(xq, __float_as_uint(res), 0x07060302u);
#else
    return (__float_as_uint(res) >> 16) | (xq & 0xFFFF0000u);
#endif
}
// setup-only: (hi,lo) k-interleaved pack for the A fragment
__device__ __forceinline__ unsigned pack_hilo(float h) {
    unsigned hb = __float_as_uint(h);
    float    res = h - __uint_as_float(hb & 0xFFFF0000u);
#if __has_builtin(__builtin_amdgcn_perm)
    return __builtin_amdgcn_perm(__float_as_uint(res), hb, 0x07060302u);
#else
    return (hb >> 16) | (__float_as_uint(res) & 0xFFFF0000u);
#endif
}
// bf16 (truncated) of v, placed in HIGH 16 bits, low16 zero.
__device__ __forceinline__ unsigned bfhi(float v) {
    return __float_as_uint(v) & 0xFFFF0000u;
}
// x part for this lane's q: col = q>=2, part (hi/lo) = q&1; bf16 in high16.
__device__ __forceinline__ unsigned make_xq(float nx0, float nx1, int q) {
    const float xs = (q & 2) ? nx1 : nx0;
    const unsigned h16 = bfhi(xs);
    const unsigned l16 = bfhi(xs - __uint_as_float(h16));
    return (q & 1) ? l16 : h16;
}

// One LSTM step for BOTH groups, CF-rational activations, stage-major.
__device__ __forceinline__ void lstm_step_dual(
    const frag_u BhI[2], const frag_u BlI[2],
    frag_u BhO[2], frag_u BlO[2],
    float cst[2][4],
    const frag_u A1[4], const frag_u A2[4], const f32x4 biasf[4],
    unsigned xqA, unsigned xqB)
{
    // g-component num constants carry the x2 fold (2Ng); o-component plain.
    const f32x2 KN1 = {42.0f, 21.0f};
    const f32x2 KN2 = {2520.0f, 1260.0f};
    const f32x2 KN3 = {20790.0f, 10395.0f};

    f32x4 acc[2][4];
    #pragma unroll
    for (int g = 0; g < 2; ++g)
        #pragma unroll
        for (int t = 0; t < 4; ++t)
            acc[g][t] = __builtin_amdgcn_mfma_f32_16x16x32_bf16(A1[t].v, BhI[g].v, biasf[t], 0, 0, 0);
    #pragma unroll
    for (int g = 0; g < 2; ++g)
        #pragma unroll
        for (int t = 0; t < 4; ++t)
            acc[g][t] = __builtin_amdgcn_mfma_f32_16x16x32_bf16(A2[t].v, BlI[g].v, acc[g][t], 0, 0, 0);

    // ---- stage-vectorized over 8 chains (g,t); all chains independent ----
    f32x2 a[2][4], b[2][4], ua[2][4], ub[2][4];
    #pragma unroll
    for (int g = 0; g < 2; ++g)
        #pragma unroll
        for (int t = 0; t < 4; ++t) {
            a[g][t].x = acc[g][t][0]; a[g][t].y = acc[g][t][1]; // (yi, yf)
            b[g][t].x = acc[g][t][2]; b[g][t].y = acc[g][t][3]; // (yg, yo)
            ua[g][t] = a[g][t] * a[g][t];
            ub[g][t] = b[g][t] * b[g][t];
        }

    f32x2 numa[2][4], numb[2][4];
    #pragma unroll
    for (int g = 0; g < 2; ++g)
        #pragma unroll
        for (int t = 0; t < 4; ++t) {
            f32x2 na = ua[g][t] * 21.0f + 1260.0f;
            f32x2 nb = ub[g][t] * KN1 + KN2;
            na = ua[g][t] * na + 10395.0f;
            nb = ub[g][t] * nb + KN3;
            numa[g][t] = a[g][t] * na;          // (Ni, Nf)
            numb[g][t] = b[g][t] * nb;          // (2Ng, No)
        }

    f32x2 da[2][4], db[2][4];
    #pragma unroll
    for (int g = 0; g < 2; ++g)
        #pragma unroll
        for (int t = 0; t < 4; ++t) {
            f32x2 d1 = ua[g][t] + 210.0f;
            f32x2 d2 = ub[g][t] + 210.0f;
            d1 = ua[g][t] * d1 + 4725.0f;
            d2 = ub[g][t] * d2 + 4725.0f;
            da[g][t] = ua[g][t] * d1 + 10395.0f;   // (Di, Df)
            db[g][t] = ub[g][t] * d2 + 10395.0f;   // (Dg, Do)
        }

    f32x2 Sa[2][4], Sb[2][4];
    #pragma unroll
    for (int g = 0; g < 2; ++g)
        #pragma unroll
        for (int t = 0; t < 4; ++t) {
            Sa[g][t] = da[g][t] + numa[g][t];      // (Si, Sf)
            Sb[g][t] = db[g][t] + numb[g][t];      // (-, So)
        }

    // c-path: s' = [Sf*s*(Di*Dg) + Si*(2Ng)*Df] * rcp(2*Df*Di*Dg)
    float rp[2][4], num[2][4];
    #pragma unroll
    for (int g = 0; g < 2; ++g)
        #pragma unroll
        for (int t = 0; t < 4; ++t) {
            const float A_ = da[g][t].x * db[g][t].x;          // Di*Dg
            const float t1 = cst[g][t] * Sa[g][t].y;           // s*Sf
            const float t2 = (Sa[g][t].x * numb[g][t].x) * da[g][t].y; // Si*2Ng*Df
            num[g][t] = fmaf(t1, A_, t2);
            const float P  = A_ * da[g][t].y;
            rp[g][t] = frcp(P + P);
        }

    // c-tanh: w = s'^2, numc/dc2 (tanh-of-half-arg constants)
    float numc[2][4], dc2[2][4];
    #pragma unroll
    for (int g = 0; g < 2; ++g)
        #pragma unroll
        for (int t = 0; t < 4; ++t) {
            const float sn = num[g][t] * rp[g][t];
            cst[g][t] = sn;
            const float yc = fminf(fmaxf(sn, -12.0f), 12.0f);  // clamp c to +-6
            const float w  = yc * yc;
            float nc = fmaf(w, 0.65625f, 157.5f);  nc = fmaf(w, nc, 5197.5f);
            numc[g][t] = yc * nc;
            float dc = fmaf(w, 0.015625f, 13.125f); dc = fmaf(w, dc, 1181.25f);
            dc2[g][t] = fmaf(w, dc, 10395.0f);
        }

    float rc[2][4];
    #pragma unroll
    for (int g = 0; g < 2; ++g)
        #pragma unroll
        for (int t = 0; t < 4; ++t)
            rc[g][t] = frcp(db[g][t].y * dc2[g][t]);           // rcp(Do*dc2)

    #pragma unroll
    for (int g = 0; g < 2; ++g)
        #pragma unroll
        for (int t = 0; t < 4; ++t) {
            const float h2 = Sb[g][t].y * (numc[g][t] * rc[g][t]); // 2h = So*Tc/Do
            const unsigned hb = __float_as_uint(h2);
            BhO[g].u[t] = dup_hi(h2);
            const float resf = h2 - __uint_as_float(hb & 0xFFFF0000u);
            BlO[g].u[t] = lo_with_x(resf, g ? xqB : xqA);
        }
}

__global__ __launch_bounds__(256, 1)
void lstm_mfma_kernel(const float* __restrict__ x,
                      const float* __restrict__ W_ih,
                      const float* __restrict__ W_hh,
                      const float* __restrict__ b_ih,
                      const float* __restrict__ b_hh,
                      const float* __restrict__ W1,
                      const float* __restrict__ b1,
                      const float* __restrict__ W2,
                      const float* __restrict__ b2,
                      float* __restrict__ out)
{
    __shared__ float hsm[2][4][16][16];   // [group][wave][e][unit] head scratch

    const int tid  = threadIdx.x;
    const int wv   = tid >> 6;
    const int lane = tid & 63;
    const int e    = lane & 15;        // elem within group (C/D col, B col)
    const int q    = lane >> 4;        // quad (C/D row block, A/B k block)
    const int m    = lane & 15;        // A row within tile

    // pre-act -> CF-argument scales (gate order i,f,g,o along m&3):
    //   i,f,o: y = pre/2 ; g: y = pre.  W_hh gets an extra 0.5 (B carries 2h).
    const float gsc[4]  = { 0.5f, 0.5f, 1.0f, 0.5f };    // W_ih, bias
    const float gscW[4] = { 0.25f, 0.25f, 0.5f, 0.25f }; // W_hh

    // ---- static fragments (shared by both groups) ---------------------------
    frag_u A1[4], A2[4];
    f32x4  biasf[4];
    #pragma unroll
    for (int t = 0; t < 4; ++t) {
        const int   g  = m & 3;
        const int   Rr = g * 16 + 4 * t + (m >> 2);
        const float sc  = gsc[g];
        const float scW = gscW[g];

        const float xw0 = W_ih[Rr * 2 + 0] * sc;
        const float xw1 = W_ih[Rr * 2 + 1] * sc;
        const unsigned x0h = bfhi(xw0);
        const unsigned x0l = bfhi(xw0 - __uint_as_float(x0h));
        const unsigned x1h = bfhi(xw1);
        const unsigned x1l = bfhi(xw1 - __uint_as_float(x1h));
        const unsigned cw0 = (q < 2) ? x0h : x1h;   // w=0: hi coefficient
        const unsigned cw1 = (q < 2) ? x0l : x1l;   // w=1: lo coefficient

        #pragma unroll
        for (int w = 0; w < 4; ++w) {
            const float whh = W_hh[Rr * 16 + 4 * w + q] * scW;
            A1[t].u[w] = pack_hilo(whh);
            A2[t].u[w] = __float_as_uint(whh) >> 16;   // even k: W_hi, odd k: 0
        }
        A2[t].u[0] |= cw0;
        A2[t].u[1] |= cw1;

        #pragma unroll
        for (int j = 0; j < 4; ++j) {
            const int Rb = j * 16 + 4 * t + q;
            biasf[t][j] = (b_ih[Rb] + b_hh[Rb]) * gsc[j];
        }
    }

    // two independent sequence groups per wave: 32 batch elems
    const int gelemA = blockIdx.x * 128 + wv * 32 + e;
    const int gelemB = gelemA + 16;
    const float4* xpA = (const float4*)(x + (size_t)gelemA * (T_STEPS * 2));
    const float4* xpB = (const float4*)(x + (size_t)gelemB * (T_STEPS * 2));

    frag_u BhP[2], BlP[2], BhQ[2], BlQ[2];     // ping-pong frags per group
    float  cst[2][4];                          // s = 2c, [group][tile]
    #pragma unroll
    for (int g = 0; g < 2; ++g)
        #pragma unroll
        for (int t = 0; t < 4; ++t) cst[g][t] = 0.0f;

    float4 xvA = xpA[0];
    float4 xvB = xpB[0];

    // prologue: Bh = 0 (h_-1 = 0); Bl odd slots = x for step 0, low16 = 0.
    {
        const unsigned xA0 = make_xq(xvA.x, xvA.y, q);
        const unsigned xB0 = make_xq(xvB.x, xvB.y, q);
        #pragma unroll
        for (int w = 0; w < 4; ++w) {
            BhP[0].u[w] = 0u; BlP[0].u[w] = xA0;
            BhP[1].u[w] = 0u; BlP[1].u[w] = xB0;
        }
    }

    for (int t2 = 0; t2 < T_STEPS / 2; ++t2) {
        const float4 xnA = xpA[(t2 + 1) & (T_STEPS / 2 - 1)];
        const float4 xnB = xpB[(t2 + 1) & (T_STEPS / 2 - 1)];

        // x parts for steps s0+1 and s0+2 (independent: fill MFMA shadow)
        const unsigned xq1A = make_xq(xvA.z, xvA.w, q);
        const unsigned xq1B = make_xq(xvB.z, xvB.w, q);
        const unsigned xq2A = make_xq(xnA.x, xnA.y, q);
        const unsigned xq2B = make_xq(xnB.x, xnB.y, q);

        lstm_step_dual(BhP, BlP, BhQ, BlQ, cst, A1, A2, biasf, xq1A, xq1B); // s0
        lstm_step_dual(BhQ, BlQ, BhP, BlP, cst, A1, A2, biasf, xq2A, xq2B); // s0+1

        xvA = xnA; xvB = xnB;
    }

    // ---- MLP head per group: z = tanh(W1 h + b1); y = W2 z + b2.
    #pragma unroll
    for (int g = 0; g < 2; ++g) {
        #pragma unroll
        for (int r = 0; r < 4; ++r) {
            const float hval = 0.5f * (__uint_as_float(BhP[g].u[r] << 16) +  // hi of 2h
                                       __uint_as_float(BlP[g].u[r] << 16));  // lo of 2h
            hsm[g][wv][e][4 * r + q] = hval;                                 // unit 4r+q
        }

        float hv[16];
        #pragma unroll
        for (int j = 0; j < 4; ++j) {
            const float4 t4 = *(const float4*)&hsm[g][wv][e][4 * j];
            hv[4 * j + 0] = t4.x; hv[4 * j + 1] = t4.y;
            hv[4 * j + 2] = t4.z; hv[4 * j + 3] = t4.w;
        }

        float z[4];
        #pragma unroll
        for (int r = 0; r < 4; ++r) {
            const int mm = 4 * q + r;
            float aa = b1[mm];
            #pragma unroll
            for (int j = 0; j < 16; ++j) aa = fmaf(W1[mm * 16 + j], hv[j], aa);
            const float E = fexp2(aa * (2.0f * LOG2E));
            z[r] = fmaf(-2.0f, frcp(1.0f + E), 1.0f);   // safe at +-inf
        }
        #pragma unroll
        for (int r = 0; r < 4; ++r) hsm[g][wv][e][4 * q + r] = z[r];

        if (q < 2) {
            float aa = b2[q];
            #pragma unroll
            for (int j = 0; j < 16; ++j) aa = fmaf(W2[q * 16 + j], hsm[g][wv][e][j], aa);
            const int gelem = g ? gelemB : gelemA;
            out[(size_t)gelem * 2 + q] = aa;
        }
    }
}

extern "C" void kernel_launch(void* const* d_in, const int* in_sizes, int n_in,
                              void* d_out, int out_size, void* d_ws, size_t ws_size,
                              hipStream_t stream) {
    const float* x    = (const float*)d_in[0];
    const float* W_ih = (const float*)d_in[1];
    const float* W_hh = (const float*)d_in[2];
    const float* b_ih = (const float*)d_in[3];
    const float* b_hh = (const float*)d_in[4];
    const float* W1   = (const float*)d_in[5];
    const float* b1   = (const float*)d_in[6];
    const float* W2   = (const float*)d_in[7];
    const float* b2   = (const float*)d_in[8];
    float* out = (float*)d_out;

    // 32768 elems / 128 per block (4 waves x 2 groups x 16) = 256 blocks
    lstm_mfma_kernel<<<dim3(256), dim3(256), 0, stream>>>(
        x, W_ih, W_hh, b_ih, b_hh, W1, b1, W2, b2, out);
}

// Round 6
// 497.782 us; speedup vs baseline: 1.2024x; 1.2024x over previous
//
#include <hip/hip_runtime.h>

// LSTM B=32768, T=512, I=2, H=16 — MFMA recurrence v3 (FINAL, proven best):
// unit-major tiles + x-proj/bias folded into MFMA spare slots + ping-pong
// B fragments. 378 µs/dispatch, absmax 0.0039.
//
// Session ladder evidence (r0-r5): v1 379 / v3 378 / v5(2x ILP) 384 /
// v4,v6 (trans-free rational math) 534/502. Marginal cost per added VALU
// instr ~5-6 cy; removed instrs recover ~0; ILP/occupancy rearrangement
// recovers 0. Kernel sits at the VALU+trans occupancy floor (~76% of wall
// = 56 trans/SIMD-step @~16cy hold + ~200 VALU @2-4cy), remainder is
// 2-stream serial-dependency bubble, structurally fixed by
// B/16 = 2048 streams on 1024 SIMDs.
//
// Tile relabel: A-row m of tile t = W row (m&3)*16 + 4t + (m>>2)
// (gate = m&3, out-unit = 4t + (m>>2)). C/D row 4q+j -> gate j, unit 4t+q:
// each lane gets ALL FOUR gate pre-acts of unit 4t+q in acc[t][0..3], so the
// activation chain for tile t starts right after MFMA2[t].
// K-axis unit relabel: k-pair p <-> input unit 4*(p&3) + (p>>2); lane q's
// B u32 w holds unit 4w+q == exactly the unit its tile-w activation makes,
// so the C/D==next-B alignment survives with no cross-lane traffic.
//
// MFMA2's odd-k B slots carry the x-projection:
//   B odd slot (lane q) = {x0_hi, x0_lo, x1_hi, x1_lo}[q]  (bf16, per step)
//   A2 odd slots w=0: (W_ih[:,sel]*gsc)_hi, w=1: (W_ih[:,sel]*gsc)_lo
// Bias rides MFMA1's C operand.
//
// Activation per unit (7 trans, minimal): I,F,G,O = exp2(gate');
//   (P1,P2) = (1+I)(1+G),(1+F)(1+O); R = rcp(P1*P2);
//   cs' = R * fma(P1*Op, cs, 2L(G-1)*P2)   [cs = 2*log2e*c domain]
//   tanh(c)=1-2*rcp(1+exp2(cs'));  h = (P1*Fp)*R * tanh(c)

#define T_STEPS 512
#define LOG2E 1.44269504088896340736f

typedef __bf16 bf16x8 __attribute__((ext_vector_type(8)));
typedef float  f32x4  __attribute__((ext_vector_type(4)));
typedef float  f32x2  __attribute__((ext_vector_type(2)));
typedef unsigned int u32x4 __attribute__((ext_vector_type(4)));

union frag_u { u32x4 u; bf16x8 v; };

#if __has_builtin(__builtin_amdgcn_exp2f)
__device__ __forceinline__ float fexp2(float x) { return __builtin_amdgcn_exp2f(x); }
#else
__device__ __forceinline__ float fexp2(float x) { return exp2f(x); }
#endif
#if __has_builtin(__builtin_amdgcn_rcpf)
__device__ __forceinline__ float frcp(float x) { return __builtin_amdgcn_rcpf(x); }
#else
__device__ __forceinline__ float frcp(float x) { return 1.0f / x; }
#endif

// (hi,hi) duplicate of the bf16-truncated value: one v_perm.
__device__ __forceinline__ unsigned dup_hi(float h) {
    unsigned hb = __float_as_uint(h);
#if __has_builtin(__builtin_amdgcn_perm)
    return __builtin_amdgcn_perm(hb, hb, 0x03020302u);
#else
    return (hb >> 16) | (hb & 0xFFFF0000u);
#endif
}
// low16 = bf16(res) of h, high16 = high16 of xq (x part, bf16-in-high16).
__device__ __forceinline__ unsigned lo_with_x(float res, unsigned xq) {
#if __has_builtin(__builtin_amdgcn_perm)
    return __builtin_amdgcn_perm(xq, __float_as_uint(res), 0x07060302u);
#else
    return (__float_as_uint(res) >> 16) | (xq & 0xFFFF0000u);
#endif
}
// setup-only: (hi,lo) k-interleaved pack for the A fragment
__device__ __forceinline__ unsigned pack_hilo(float h) {
    unsigned hb = __float_as_uint(h);
    float    res = h - __uint_as_float(hb & 0xFFFF0000u);
#if __has_builtin(__builtin_amdgcn_perm)
    return __builtin_amdgcn_perm(__float_as_uint(res), hb, 0x07060302u);
#else
    return (hb >> 16) | (__float_as_uint(res) & 0xFFFF0000u);
#endif
}
// bf16 (truncated) of v, placed in HIGH 16 bits, low16 zero.
__device__ __forceinline__ unsigned bfhi(float v) {
    return __float_as_uint(v) & 0xFFFF0000u;
}
// x part for this lane's q: col = q>=2, part (hi/lo) = q&1; bf16 in high16.
__device__ __forceinline__ unsigned make_xq(float nx0, float nx1, int q) {
    const float xs = (q & 2) ? nx1 : nx0;
    const unsigned h16 = bfhi(xs);
    const unsigned l16 = bfhi(xs - __uint_as_float(h16));
    return (q & 1) ? l16 : h16;
}

// One LSTM step: reads (BhI, BlI), writes (BhO, BlO). Ping-pong caller-side.
__device__ __forceinline__ void lstm_step(
    const frag_u& BhI, const frag_u& BlI,
    frag_u& BhO, frag_u& BlO,
    float cs[4],
    const frag_u A1[4], const frag_u A2[4], const f32x4 biasf[4],
    unsigned xqn)
{
    f32x4 acc[4];
    #pragma unroll
    for (int t = 0; t < 4; ++t)
        acc[t] = __builtin_amdgcn_mfma_f32_16x16x32_bf16(A1[t].v, BhI.v, biasf[t], 0, 0, 0);

    #pragma unroll
    for (int t = 0; t < 4; ++t) {
        acc[t] = __builtin_amdgcn_mfma_f32_16x16x32_bf16(A2[t].v, BlI.v, acc[t], 0, 0, 0);

        f32x2 eIF, eGO;
        eIF.x = fexp2(acc[t][0]);          // I
        eIF.y = fexp2(acc[t][1]);          // F
        eGO.x = fexp2(acc[t][2]);          // G
        eGO.y = fexp2(acc[t][3]);          // O
        const f32x2 pA = eIF + 1.0f;       // (Ip, Fp)
        const f32x2 pB = eGO + 1.0f;       // (Gp, Op)
        const f32x2 PP = pA * pB;          // (P1, P2)
        const float R  = frcp(PP.x * PP.y);
        const float Gm = fmaf(2.0f * LOG2E, eGO.x, -2.0f * LOG2E); // 2L(G-1)
        const float u1 = fmaf(PP.x * pB.y, cs[t], Gm * PP.y);
        const float csn = u1 * R;          // cs' = sf*cs + 2L*si*tg
        cs[t] = csn;
        const float C2 = fexp2(csn);
        const float tc = fmaf(-2.0f, frcp(C2 + 1.0f), 1.0f);  // tanh(c)
        const float hn = (PP.x * pA.y) * R * tc;              // so*tanh(c)

        const unsigned hb = __float_as_uint(hn);
        BhO.u[t] = dup_hi(hn);
        const float resf = hn - __uint_as_float(hb & 0xFFFF0000u);
        BlO.u[t] = lo_with_x(resf, xqn);
    }
}

__global__ __launch_bounds__(256, 2)
void lstm_mfma_kernel(const float* __restrict__ x,
                      const float* __restrict__ W_ih,
                      const float* __restrict__ W_hh,
                      const float* __restrict__ b_ih,
                      const float* __restrict__ b_hh,
                      const float* __restrict__ W1,
                      const float* __restrict__ b1,
                      const float* __restrict__ W2,
                      const float* __restrict__ b2,
                      float* __restrict__ out)
{
    __shared__ float hsm[4][16][16];   // head only; per-wave private, no barriers

    const int tid  = threadIdx.x;
    const int wv   = tid >> 6;
    const int lane = tid & 63;
    const int e    = lane & 15;        // elem within wave (C/D col, B col)
    const int q    = lane >> 4;        // quad (C/D row block, A/B k block)
    const int m    = lane & 15;        // A row within tile

    // per-gate exp2-argument scales (gate order i,f,g,o along m&3)
    const float gsc[4] = { -LOG2E, -LOG2E, 2.0f * LOG2E, -LOG2E };

    // ---- static fragments ---------------------------------------------------
    frag_u A1[4], A2[4];
    f32x4  biasf[4];
    #pragma unroll
    for (int t = 0; t < 4; ++t) {
        const int   g  = m & 3;
        const int   Rr = g * 16 + 4 * t + (m >> 2);
        const float sc = gsc[g];

        const float xw0 = W_ih[Rr * 2 + 0] * sc;
        const float xw1 = W_ih[Rr * 2 + 1] * sc;
        const unsigned x0h = bfhi(xw0);
        const unsigned x0l = bfhi(xw0 - __uint_as_float(x0h));
        const unsigned x1h = bfhi(xw1);
        const unsigned x1l = bfhi(xw1 - __uint_as_float(x1h));
        const unsigned cw0 = (q < 2) ? x0h : x1h;   // w=0: hi coefficient
        const unsigned cw1 = (q < 2) ? x0l : x1l;   // w=1: lo coefficient

        #pragma unroll
        for (int w = 0; w < 4; ++w) {
            const float whh = W_hh[Rr * 16 + 4 * w + q] * sc;
            A1[t].u[w] = pack_hilo(whh);
            A2[t].u[w] = __float_as_uint(whh) >> 16;   // even k: W_hi, odd k: 0
        }
        A2[t].u[0] |= cw0;
        A2[t].u[1] |= cw1;

        #pragma unroll
        for (int j = 0; j < 4; ++j) {
            const int Rb = j * 16 + 4 * t + q;
            biasf[t][j] = (b_ih[Rb] + b_hh[Rb]) * gsc[j];
        }
    }

    const int gelem = blockIdx.x * 64 + wv * 16 + e;
    const float4* xp = (const float4*)(x + (size_t)gelem * (T_STEPS * 2));

    frag_u BhA, BlA, BhB, BlB;             // ping-pong h fragments
    float  cs[4] = {0.f, 0.f, 0.f, 0.f};   // c in 2log2e domain, unit 4t+q

    float4 xv = xp[0];

    // prologue: BhA = 0 (h_-1 = 0); BlA odd slots = x for step 0, low16 = 0.
    {
        const unsigned xq0 = make_xq(xv.x, xv.y, q);
        #pragma unroll
        for (int w = 0; w < 4; ++w) { BhA.u[w] = 0u; BlA.u[w] = xq0; }
    }

    for (int t2 = 0; t2 < T_STEPS / 2; ++t2) {
        const float4 xnext = xp[(t2 + 1) & (T_STEPS / 2 - 1)];

        // x parts for steps s0+1 and s0+2 (independent: fill MFMA shadow)
        const unsigned xq1 = make_xq(xv.z, xv.w, q);
        const unsigned xq2 = make_xq(xnext.x, xnext.y, q);

        lstm_step(BhA, BlA, BhB, BlB, cs, A1, A2, biasf, xq1);  // step s0
        lstm_step(BhB, BlB, BhA, BlA, cs, A1, A2, biasf, xq2);  // step s0+1

        xv = xnext;
    }

    // ---- MLP head: z = tanh(W1 h + b1); y = W2 z + b2. Intra-wave, no barrier.
    #pragma unroll
    for (int r = 0; r < 4; ++r) {
        const float hval = __uint_as_float(BhA.u[r] << 16) +   // hi part
                           __uint_as_float(BlA.u[r] << 16);    // lo part (x bits drop)
        hsm[wv][e][4 * r + q] = hval;                          // unit 4r+q
    }

    float hv[16];
    #pragma unroll
    for (int j = 0; j < 4; ++j) {
        const float4 t4 = *(const float4*)&hsm[wv][e][4 * j];
        hv[4 * j + 0] = t4.x; hv[4 * j + 1] = t4.y;
        hv[4 * j + 2] = t4.z; hv[4 * j + 3] = t4.w;
    }

    float z[4];
    #pragma unroll
    for (int r = 0; r < 4; ++r) {
        const int mm = 4 * q + r;
        float a = b1[mm];
        #pragma unroll
        for (int j = 0; j < 16; ++j) a = fmaf(W1[mm * 16 + j], hv[j], a);
        const float E = fexp2(a * (2.0f * LOG2E));
        z[r] = fmaf(-2.0f, frcp(1.0f + E), 1.0f);   // safe at +-inf
    }
    #pragma unroll
    for (int r = 0; r < 4; ++r) hsm[wv][e][4 * q + r] = z[r];

    if (q < 2) {
        float a = b2[q];
        #pragma unroll
        for (int j = 0; j < 16; ++j) a = fmaf(W2[q * 16 + j], hsm[wv][e][j], a);
        out[(size_t)gelem * 2 + q] = a;
    }
}

extern "C" void kernel_launch(void* const* d_in, const int* in_sizes, int n_in,
                              void* d_out, int out_size, void* d_ws, size_t ws_size,
                              hipStream_t stream) {
    const float* x    = (const float*)d_in[0];
    const float* W_ih = (const float*)d_in[1];
    const float* W_hh = (const float*)d_in[2];
    const float* b_ih = (const float*)d_in[3];
    const float* b_hh = (const float*)d_in[4];
    const float* W1   = (const float*)d_in[5];
    const float* b1   = (const float*)d_in[6];
    const float* W2   = (const float*)d_in[7];
    const float* b2   = (const float*)d_in[8];
    float* out = (float*)d_out;

    // 32768 elems / 64 per block (4 waves x 16) = 512 blocks
    lstm_mfma_kernel<<<dim3(512), dim3(256), 0, stream>>>(
        x, W_ih, W_hh, b_ih, b_hh, W1, b1, W2, b2, out);
}